// Round 5
// baseline (449.041 us; speedup 1.0000x reference)
//
#include <hip/hip_runtime.h>

// AttGNN: GAT + GCN on sparse (~1%) 8192-node graph.
// R6: ONLINE fused compact+GAT in K23. Scores are tanh(.) in [-1,1] so
// softmax needs NO max subtraction -> e=exp(tanh(s_i+t_j)) is final at append
// time; every 16 compacted entries trigger one (pp,c16) gather batch, hidden
// under the sup HBM stream (prefetch-ahead). Removes the globally serialized
// gather phase (all 8192 waves = one generation; phases were lockstep).
// No __syncthreads in K23: LDS is wave-private, batch triggers wave-uniform.
// Floor = one 256 MB sup read (~41 us) + ~320 us harness poison-fill.

#define N_NODES 8192
#define D_IN    128
#define D_GAT   64
#define SLOTS   256          // max nnz/row; binomial(8192,0.01) mean ~83, max ~120

// Compact 4 consecutive elements (one float4) of row j held by this lane.
// Wave-private `base`; appends col->LDS, e=exp(tanh(s_i+tj))->LDS, and
// writes (col,val) through to HBM for K4.
#define COMPACT4(VX, QQ)                                                      \
    {                                                                         \
        float ee4[4] = {VX.x, VX.y, VX.z, VX.w};                              \
        _Pragma("unroll")                                                     \
        for (int u = 0; u < 4; ++u) {                                         \
            const int i = (QQ) * 4 + u;                                       \
            const float vv = ee4[u] + ((i == j) ? 1.0f : 0.0f); /* sup2 */    \
            const bool keep = vv > 0.f;                                       \
            const unsigned long long mask = __ballot(keep);                   \
            if (keep) {                                                       \
                const int pos = base +                                        \
                    __popcll(mask & ((1ull << lane) - 1ull));                 \
                if (pos < SLOTS) {                                            \
                    clr[pos]  = i;                                            \
                    we[pos]   = __expf(tanhf(s[i] + tj));                     \
                    colj[pos] = i;                                            \
                    valj[pos] = vv;                                           \
                }                                                             \
            }                                                                 \
            base += __popcll(mask);                                           \
        }                                                                     \
    }

// Process 16 compacted entries [done, done+16) through the (pp,c16) gather.
#define BATCH16()                                                             \
    {                                                                         \
        const int p0 = done + pp, p1 = p0 + 4, p2 = p0 + 8, p3 = p0 + 12;     \
        const float e0 = we[p0], e1 = we[p1], e2 = we[p2], e3 = we[p3];       \
        lsum += (e0 + e1) + (e2 + e3);                                        \
        const float4 h0 = *(const float4*)(h + clr[p0] * D_GAT + c16);        \
        const float4 h1 = *(const float4*)(h + clr[p1] * D_GAT + c16);        \
        const float4 h2 = *(const float4*)(h + clr[p2] * D_GAT + c16);        \
        const float4 h3 = *(const float4*)(h + clr[p3] * D_GAT + c16);        \
        a0.x += e0*h0.x; a0.y += e0*h0.y; a0.z += e0*h0.z; a0.w += e0*h0.w;   \
        a1.x += e1*h1.x; a1.y += e1*h1.y; a1.z += e1*h1.z; a1.w += e1*h1.w;   \
        a2.x += e2*h2.x; a2.y += e2*h2.y; a2.z += e2*h2.z; a2.w += e2*h2.w;   \
        a3.x += e3*h3.x; a3.y += e3*h3.y; a3.z += e3*h3.z; a3.w += e3*h3.w;   \
        done += 16;                                                           \
    }

// ---------------- K1: h = feat@W_map ; s = h@U ; t = h@V --------------------
__global__ __launch_bounds__(256) void k1_map(
    const float* __restrict__ feat, const float* __restrict__ W_map,
    const float* __restrict__ U, const float* __restrict__ V,
    float* __restrict__ h, float* __restrict__ s, float* __restrict__ t)
{
    const int wid  = threadIdx.x >> 6;
    const int lane = threadIdx.x & 63;
    const int row = blockIdx.x * 4 + wid;
    __shared__ float f[4 * D_IN];
    if (threadIdx.x < 128)
        ((float4*)f)[threadIdx.x] =
            ((const float4*)(feat + (size_t)blockIdx.x * 4 * D_IN))[threadIdx.x];
    __syncthreads();
    const float* fr = f + wid * D_IN;
    float acc = 0.f;
#pragma unroll 8
    for (int k = 0; k < D_IN; ++k)
        acc += fr[k] * W_map[k * D_GAT + lane];
    h[row * D_GAT + lane] = acc;
    float sv = acc * U[lane];
    float tv = acc * V[lane];
#pragma unroll
    for (int off = 32; off > 0; off >>= 1) {
        sv += __shfl_xor(sv, off);
        tv += __shfl_xor(tv, off);
    }
    if (lane == 0) { s[row] = sv; t[row] = tv; }
}

// ---------------- K23: online compact+GAT, one row per wave -----------------
__global__ __launch_bounds__(256) void k23_compact_gat(
    const float* __restrict__ sup, const float* __restrict__ h,
    const float* __restrict__ s, const float* __restrict__ t,
    const float* __restrict__ b,
    int* __restrict__ cnt, int* __restrict__ col, float* __restrict__ val,
    float* __restrict__ gat)
{
    const int wid  = threadIdx.x >> 6;
    const int lane = threadIdx.x & 63;
    const int j = blockIdx.x * 4 + wid;

    __shared__ int   cl_s[4][SLOTS];   // 4 KB  compacted neighbor cols
    __shared__ float we_s[4][SLOTS];   // 4 KB  exp(tanh(score)) per neighbor
    int*   clr = cl_s[wid];
    float* we  = we_s[wid];
    int*   colj = col + j * SLOTS;
    float* valj = val + j * SLOTS;

    const float tj  = t[j] + b[0];
    const int   c16 = (lane & 15) * 4;
    const int   pp  = lane >> 4;

    const float4* row4 = (const float4*)(sup + (size_t)j * N_NODES);
    float4 v0 = row4[lane];
    float4 v1 = row4[lane + 64];
    int base = 0, done = 0;
    float lsum = 0.f;
    float4 a0 = make_float4(0,0,0,0), a1 = a0, a2 = a0, a3 = a0;

    for (int it = 0; it < 16; ++it) {
        const int q = lane + it * 128;
        float4 n0 = make_float4(0,0,0,0), n1 = n0;
        if (it < 15) { n0 = row4[q + 128]; n1 = row4[q + 192]; }  // prefetch
        COMPACT4(v0, q);
        COMPACT4(v1, q + 64);
        const int avail = (base < SLOTS) ? base : SLOTS;
        while (done + 16 <= avail) BATCH16();   // gathers hide under n0/n1
        v0 = n0; v1 = n1;
    }

    const int m = (base < SLOTS) ? base : SLOTS;
    while (done + 16 <= m) BATCH16();
    // masked tail (< 16 entries)
    {
        const int p0 = done + pp, p1 = p0 + 4, p2 = p0 + 8, p3 = p0 + 12;
        if (p0 < m) { const float e = we[p0]; lsum += e;
            const float4 v = *(const float4*)(h + clr[p0] * D_GAT + c16);
            a0.x += e*v.x; a0.y += e*v.y; a0.z += e*v.z; a0.w += e*v.w; }
        if (p1 < m) { const float e = we[p1]; lsum += e;
            const float4 v = *(const float4*)(h + clr[p1] * D_GAT + c16);
            a1.x += e*v.x; a1.y += e*v.y; a1.z += e*v.z; a1.w += e*v.w; }
        if (p2 < m) { const float e = we[p2]; lsum += e;
            const float4 v = *(const float4*)(h + clr[p2] * D_GAT + c16);
            a2.x += e*v.x; a2.y += e*v.y; a2.z += e*v.z; a2.w += e*v.w; }
        if (p3 < m) { const float e = we[p3]; lsum += e;
            const float4 v = *(const float4*)(h + clr[p3] * D_GAT + c16);
            a3.x += e*v.x; a3.y += e*v.y; a3.z += e*v.z; a3.w += e*v.w; }
    }
    if (lane == 0) cnt[j] = m;

    float4 acc;
    acc.x = (a0.x + a1.x) + (a2.x + a3.x);
    acc.y = (a0.y + a1.y) + (a2.y + a3.y);
    acc.z = (a0.z + a1.z) + (a2.z + a3.z);
    acc.w = (a0.w + a1.w) + (a2.w + a3.w);
#pragma unroll
    for (int off = 16; off <= 32; off <<= 1) {
        acc.x += __shfl_xor(acc.x, off); acc.y += __shfl_xor(acc.y, off);
        acc.z += __shfl_xor(acc.z, off); acc.w += __shfl_xor(acc.w, off);
        lsum  += __shfl_xor(lsum, off);
    }
    if (pp == 0) {
        const float inv = 1.0f / lsum;
        float4 o;
        o.x = tanhf(acc.x * inv); o.y = tanhf(acc.y * inv);
        o.z = tanhf(acc.z * inv); o.w = tanhf(acc.w * inv);
        *(float4*)(gat + j * D_GAT + c16) = o;
    }
}

// ---------------- K4: agg = sup2@gat ; out = normalize(relu(agg@W_gcn)) ----
__global__ __launch_bounds__(256) void k4_gcn(
    const float* __restrict__ gat, const float* __restrict__ W_gcn,
    const int* __restrict__ cnt, const int* __restrict__ col,
    const float* __restrict__ val, float* __restrict__ out)
{
    const int wid  = threadIdx.x >> 6;
    const int lane = threadIdx.x & 63;
    const int j = blockIdx.x * 4 + wid;
    const int m = cnt[j];
    const int*   colj = col + j * SLOTS;
    const float* valj = val + j * SLOTS;
    __shared__ int   cl_s[4][SLOTS];
    __shared__ float wv_s[4][SLOTS];
    __shared__ float a_s[4][D_GAT];
    int*   cl = cl_s[wid];
    float* wv = wv_s[wid];
    float* a  = a_s[wid];
    for (int p = lane; p < m; p += 64) { cl[p] = colj[p]; wv[p] = valj[p]; }
    __syncthreads();

    const int c16 = (lane & 15) * 4;
    const int pp  = lane >> 4;
    float4 a0 = make_float4(0,0,0,0), a1 = a0, a2 = a0, a3 = a0;
    for (int base = 0; base < m; base += 16) {
        const int p0 = base + pp, p1 = p0 + 4, p2 = p0 + 8, p3 = p0 + 12;
        if (p0 < m) { const float wp = wv[p0];
            const float4 v = *(const float4*)(gat + cl[p0] * D_GAT + c16);
            a0.x += wp*v.x; a0.y += wp*v.y; a0.z += wp*v.z; a0.w += wp*v.w; }
        if (p1 < m) { const float wp = wv[p1];
            const float4 v = *(const float4*)(gat + cl[p1] * D_GAT + c16);
            a1.x += wp*v.x; a1.y += wp*v.y; a1.z += wp*v.z; a1.w += wp*v.w; }
        if (p2 < m) { const float wp = wv[p2];
            const float4 v = *(const float4*)(gat + cl[p2] * D_GAT + c16);
            a2.x += wp*v.x; a2.y += wp*v.y; a2.z += wp*v.z; a2.w += wp*v.w; }
        if (p3 < m) { const float wp = wv[p3];
            const float4 v = *(const float4*)(gat + cl[p3] * D_GAT + c16);
            a3.x += wp*v.x; a3.y += wp*v.y; a3.z += wp*v.z; a3.w += wp*v.w; }
    }
    float4 acc;
    acc.x = (a0.x + a1.x) + (a2.x + a3.x);
    acc.y = (a0.y + a1.y) + (a2.y + a3.y);
    acc.z = (a0.z + a1.z) + (a2.z + a3.z);
    acc.w = (a0.w + a1.w) + (a2.w + a3.w);
#pragma unroll
    for (int off = 16; off <= 32; off <<= 1) {
        acc.x += __shfl_xor(acc.x, off); acc.y += __shfl_xor(acc.y, off);
        acc.z += __shfl_xor(acc.z, off); acc.w += __shfl_xor(acc.w, off);
    }
    if (pp == 0) *(float4*)(a + c16) = acc;
    __syncthreads();     // a_s visibility (intra-wave, but keep it simple/safe)

    float o = 0.f;
#pragma unroll 8
    for (int d = 0; d < D_GAT; ++d)
        o += a[d] * W_gcn[d * D_GAT + lane];   // a broadcast, W_gcn L1-hot
    o = fmaxf(o, 0.f);

    float ss = o * o;
#pragma unroll
    for (int off = 32; off > 0; off >>= 1) ss += __shfl_xor(ss, off);
    const float nrm = sqrtf(ss);
    out[j * D_GAT + lane] = o / fmaxf(nrm, 1e-12f);
}

extern "C" void kernel_launch(void* const* d_in, const int* in_sizes, int n_in,
                              void* d_out, int out_size, void* d_ws, size_t ws_size,
                              hipStream_t stream) {
    const float* feat  = (const float*)d_in[0];  // [N,128]
    const float* sup   = (const float*)d_in[1];  // [N,N]
    const float* W_map = (const float*)d_in[2];  // [128,64]
    const float* b_map = (const float*)d_in[3];  // [1]
    const float* U     = (const float*)d_in[4];  // [64,1]
    const float* V     = (const float*)d_in[5];  // [64,1]
    const float* W_gcn = (const float*)d_in[6];  // [64,64]
    float* out = (float*)d_out;

    char* ws = (char*)d_ws;
    float* h   = (float*)(ws);                         // 2 MB
    float* gat = (float*)(ws + (2u << 20));            // 2 MB
    float* s   = (float*)(ws + (4u << 20));            // 32 KB
    float* t   = (float*)(ws + (4u << 20) + 32768);    // 32 KB
    int*   cnt = (int*)  (ws + (4u << 20) + 65536);    // 32 KB
    int*   col = (int*)  (ws + (4u << 20) + 98304);    // 8 MB
    float* val = (float*)(ws + (12u << 20) + 98304);   // 8 MB  (~20.1 MB total)

    k1_map<<<N_NODES / 4, 256, 0, stream>>>(feat, W_map, U, V, h, s, t);
    k23_compact_gat<<<N_NODES / 4, 256, 0, stream>>>(
        sup, h, s, t, b_map, cnt, col, val, gat);
    k4_gcn<<<N_NODES / 4, 256, 0, stream>>>(gat, W_gcn, cnt, col, val, out);
}

// Round 6
// 405.359 us; speedup vs baseline: 1.1078x; 1.1078x over previous
//
#include <hip/hip_runtime.h>

// AttGNN: GAT + GCN on sparse (~1%) 8192-node graph.
// R7: revert R6's online interleave (latency-bound, 1.0 TB/s stream — R6
// counters). R5 topology (K1 / fused compact+GAT / K4) + two local wins:
//  (a) single-pass NO-MAX softmax: tanh in [-1,1] -> exp can't overflow,
//      so e=exp(tanh(s_i+t_j)) is final; deletes one list pass + lmax reduce
//      (numerics validated by R6's pass, absmax 9.8e-4);
//  (b) 4-deep outstanding float4 loads on the 256 MB sup stream.
// Cooperative grid.sync quarantined (R2/R3 container kills).
// Floor = sup stream (~35-41 us; R6 showed ~40% L3-resident) + ~320 us
// harness poison-fill visible in dur_us.

#define N_NODES 8192
#define D_IN    128
#define D_GAT   64
#define SLOTS   256          // max nnz/row; binomial(8192,0.01) mean ~83, max ~120

// Compact 4 consecutive elements (one float4) of row j held by this lane
// into LDS (clr/vvr). Wave-private: `base` is wave-uniform, no atomics.
#define COMPACT4(VX, QQ)                                                      \
    {                                                                         \
        float ee4[4] = {VX.x, VX.y, VX.z, VX.w};                              \
        _Pragma("unroll")                                                     \
        for (int u = 0; u < 4; ++u) {                                         \
            const int i = (QQ) * 4 + u;                                       \
            const float vv = ee4[u] + ((i == j) ? 1.0f : 0.0f); /* sup2 */    \
            const bool keep = vv > 0.f;                                       \
            const unsigned long long mask = __ballot(keep);                   \
            if (keep) {                                                       \
                const int pos = base +                                        \
                    __popcll(mask & ((1ull << lane) - 1ull));                 \
                if (pos < SLOTS) { clr[pos] = i; vvr[pos] = vv; }             \
            }                                                                 \
            base += __popcll(mask);                                           \
        }                                                                     \
    }

// ---------------- K1: h = feat@W_map ; s = h@U ; t = h@V --------------------
__global__ __launch_bounds__(256) void k1_map(
    const float* __restrict__ feat, const float* __restrict__ W_map,
    const float* __restrict__ U, const float* __restrict__ V,
    float* __restrict__ h, float* __restrict__ s, float* __restrict__ t)
{
    const int wid  = threadIdx.x >> 6;
    const int lane = threadIdx.x & 63;
    const int row = blockIdx.x * 4 + wid;
    __shared__ float f[4 * D_IN];
    if (threadIdx.x < 128)
        ((float4*)f)[threadIdx.x] =
            ((const float4*)(feat + (size_t)blockIdx.x * 4 * D_IN))[threadIdx.x];
    __syncthreads();
    const float* fr = f + wid * D_IN;
    float acc = 0.f;
#pragma unroll 8
    for (int k = 0; k < D_IN; ++k)
        acc += fr[k] * W_map[k * D_GAT + lane];
    h[row * D_GAT + lane] = acc;
    float sv = acc * U[lane];
    float tv = acc * V[lane];
#pragma unroll
    for (int off = 32; off > 0; off >>= 1) {
        sv += __shfl_xor(sv, off);
        tv += __shfl_xor(tv, off);
    }
    if (lane == 0) { s[row] = sv; t[row] = tv; }
}

// ---------------- K23: compact sup2 row j -> LDS, then GAT row j ------------
// 4 rows/block (one wave each). Phase A: stream row (4-deep), ballot-compact
// into LDS. Phase B: ONE pass: write-through (col,val) for K4 + w=exp(tanh),
// lsum. Phase C: (pp,c16) weighted h-gather, unroll-4.
__global__ __launch_bounds__(256) void k23_compact_gat(
    const float* __restrict__ sup, const float* __restrict__ h,
    const float* __restrict__ s, const float* __restrict__ t,
    const float* __restrict__ b,
    int* __restrict__ cnt, int* __restrict__ col, float* __restrict__ val,
    float* __restrict__ gat)
{
    const int wid  = threadIdx.x >> 6;
    const int lane = threadIdx.x & 63;
    const int j = blockIdx.x * 4 + wid;

    __shared__ int   cl_s[4][SLOTS];   // 4 KB  compacted neighbor cols
    __shared__ float vv_s[4][SLOTS];   // 4 KB  compacted sup2 values
    __shared__ float w_s[4][SLOTS];    // 4 KB  softmax weights
    int*   clr = cl_s[wid];
    float* vvr = vv_s[wid];
    float* w   = w_s[wid];

    // --- Phase A: stream 32 KB row, 4 outstanding float4/lane ---
    const float4* row4 = (const float4*)(sup + (size_t)j * N_NODES);
    int base = 0;                          // wave-uniform running count
    for (int q = lane; q < N_NODES / 4; q += 256) {
        float4 v0 = row4[q];
        float4 v1 = row4[q + 64];
        float4 v2 = row4[q + 128];
        float4 v3 = row4[q + 192];
        COMPACT4(v0, q);
        COMPACT4(v1, q + 64);
        COMPACT4(v2, q + 128);
        COMPACT4(v3, q + 192);
    }
    const int m = (base < SLOTS) ? base : SLOTS;
    __syncthreads();                       // LDS lists visible across lanes

    // --- Phase B: single pass: K4 write-through + w=exp(tanh(s_i+tj)), sum --
    int*   colj = col + j * SLOTS;
    float* valj = val + j * SLOTS;
    const float tj = t[j] + b[0];
    float lsum = 0.f;
    for (int p = lane; p < m; p += 64) {
        const int ci = clr[p];
        colj[p] = ci;
        valj[p] = vvr[p];
        const float e = __expf(tanhf(s[ci] + tj));  // no-max: tanh in [-1,1]
        w[p] = e;
        lsum += e;
    }
    if (lane == 0) cnt[j] = m;
#pragma unroll
    for (int off = 32; off > 0; off >>= 1) lsum += __shfl_xor(lsum, off);
    __syncthreads();                       // w[] visible across lanes

    // --- Phase C: gather-aggregate over h: lane=(pp,c16), unroll-4 ---
    const int c16 = (lane & 15) * 4;
    const int pp  = lane >> 4;
    float4 a0 = make_float4(0,0,0,0), a1 = a0, a2 = a0, a3 = a0;
    for (int bse = 0; bse < m; bse += 16) {
        const int p0 = bse + pp, p1 = p0 + 4, p2 = p0 + 8, p3 = p0 + 12;
        if (p0 < m) { const float wp = w[p0];
            const float4 v = *(const float4*)(h + clr[p0] * D_GAT + c16);
            a0.x += wp*v.x; a0.y += wp*v.y; a0.z += wp*v.z; a0.w += wp*v.w; }
        if (p1 < m) { const float wp = w[p1];
            const float4 v = *(const float4*)(h + clr[p1] * D_GAT + c16);
            a1.x += wp*v.x; a1.y += wp*v.y; a1.z += wp*v.z; a1.w += wp*v.w; }
        if (p2 < m) { const float wp = w[p2];
            const float4 v = *(const float4*)(h + clr[p2] * D_GAT + c16);
            a2.x += wp*v.x; a2.y += wp*v.y; a2.z += wp*v.z; a2.w += wp*v.w; }
        if (p3 < m) { const float wp = w[p3];
            const float4 v = *(const float4*)(h + clr[p3] * D_GAT + c16);
            a3.x += wp*v.x; a3.y += wp*v.y; a3.z += wp*v.z; a3.w += wp*v.w; }
    }
    float4 acc;
    acc.x = (a0.x + a1.x) + (a2.x + a3.x);
    acc.y = (a0.y + a1.y) + (a2.y + a3.y);
    acc.z = (a0.z + a1.z) + (a2.z + a3.z);
    acc.w = (a0.w + a1.w) + (a2.w + a3.w);
#pragma unroll
    for (int off = 16; off <= 32; off <<= 1) {
        acc.x += __shfl_xor(acc.x, off); acc.y += __shfl_xor(acc.y, off);
        acc.z += __shfl_xor(acc.z, off); acc.w += __shfl_xor(acc.w, off);
    }
    if (pp == 0) {
        const float inv = 1.0f / lsum;
        float4 o;
        o.x = tanhf(acc.x * inv); o.y = tanhf(acc.y * inv);
        o.z = tanhf(acc.z * inv); o.w = tanhf(acc.w * inv);
        *(float4*)(gat + j * D_GAT + c16) = o;
    }
}

// ---------------- K4: agg = sup2@gat ; out = normalize(relu(agg@W_gcn)) ----
__global__ __launch_bounds__(256) void k4_gcn(
    const float* __restrict__ gat, const float* __restrict__ W_gcn,
    const int* __restrict__ cnt, const int* __restrict__ col,
    const float* __restrict__ val, float* __restrict__ out)
{
    const int wid  = threadIdx.x >> 6;
    const int lane = threadIdx.x & 63;
    const int j = blockIdx.x * 4 + wid;
    const int m = cnt[j];
    const int*   colj = col + j * SLOTS;
    const float* valj = val + j * SLOTS;
    __shared__ int   cl_s[4][SLOTS];
    __shared__ float wv_s[4][SLOTS];
    __shared__ float a_s[4][D_GAT];
    int*   cl = cl_s[wid];
    float* wv = wv_s[wid];
    float* a  = a_s[wid];
    for (int p = lane; p < m; p += 64) { cl[p] = colj[p]; wv[p] = valj[p]; }
    __syncthreads();

    const int c16 = (lane & 15) * 4;
    const int pp  = lane >> 4;
    float4 a0 = make_float4(0,0,0,0), a1 = a0, a2 = a0, a3 = a0;
    for (int base = 0; base < m; base += 16) {
        const int p0 = base + pp, p1 = p0 + 4, p2 = p0 + 8, p3 = p0 + 12;
        if (p0 < m) { const float wp = wv[p0];
            const float4 v = *(const float4*)(gat + cl[p0] * D_GAT + c16);
            a0.x += wp*v.x; a0.y += wp*v.y; a0.z += wp*v.z; a0.w += wp*v.w; }
        if (p1 < m) { const float wp = wv[p1];
            const float4 v = *(const float4*)(gat + cl[p1] * D_GAT + c16);
            a1.x += wp*v.x; a1.y += wp*v.y; a1.z += wp*v.z; a1.w += wp*v.w; }
        if (p2 < m) { const float wp = wv[p2];
            const float4 v = *(const float4*)(gat + cl[p2] * D_GAT + c16);
            a2.x += wp*v.x; a2.y += wp*v.y; a2.z += wp*v.z; a2.w += wp*v.w; }
        if (p3 < m) { const float wp = wv[p3];
            const float4 v = *(const float4*)(gat + cl[p3] * D_GAT + c16);
            a3.x += wp*v.x; a3.y += wp*v.y; a3.z += wp*v.z; a3.w += wp*v.w; }
    }
    float4 acc;
    acc.x = (a0.x + a1.x) + (a2.x + a3.x);
    acc.y = (a0.y + a1.y) + (a2.y + a3.y);
    acc.z = (a0.z + a1.z) + (a2.z + a3.z);
    acc.w = (a0.w + a1.w) + (a2.w + a3.w);
#pragma unroll
    for (int off = 16; off <= 32; off <<= 1) {
        acc.x += __shfl_xor(acc.x, off); acc.y += __shfl_xor(acc.y, off);
        acc.z += __shfl_xor(acc.z, off); acc.w += __shfl_xor(acc.w, off);
    }
    if (pp == 0) *(float4*)(a + c16) = acc;
    __syncthreads();     // a_s visibility (intra-wave, but keep it simple/safe)

    float o = 0.f;
#pragma unroll 8
    for (int d = 0; d < D_GAT; ++d)
        o += a[d] * W_gcn[d * D_GAT + lane];   // a broadcast, W_gcn L1-hot
    o = fmaxf(o, 0.f);

    float ss = o * o;
#pragma unroll
    for (int off = 32; off > 0; off >>= 1) ss += __shfl_xor(ss, off);
    const float nrm = sqrtf(ss);
    out[j * D_GAT + lane] = o / fmaxf(nrm, 1e-12f);
}

extern "C" void kernel_launch(void* const* d_in, const int* in_sizes, int n_in,
                              void* d_out, int out_size, void* d_ws, size_t ws_size,
                              hipStream_t stream) {
    const float* feat  = (const float*)d_in[0];  // [N,128]
    const float* sup   = (const float*)d_in[1];  // [N,N]
    const float* W_map = (const float*)d_in[2];  // [128,64]
    const float* b_map = (const float*)d_in[3];  // [1]
    const float* U     = (const float*)d_in[4];  // [64,1]
    const float* V     = (const float*)d_in[5];  // [64,1]
    const float* W_gcn = (const float*)d_in[6];  // [64,64]
    float* out = (float*)d_out;

    char* ws = (char*)d_ws;
    float* h   = (float*)(ws);                         // 2 MB
    float* gat = (float*)(ws + (2u << 20));            // 2 MB
    float* s   = (float*)(ws + (4u << 20));            // 32 KB
    float* t   = (float*)(ws + (4u << 20) + 32768);    // 32 KB
    int*   cnt = (int*)  (ws + (4u << 20) + 65536);    // 32 KB
    int*   col = (int*)  (ws + (4u << 20) + 98304);    // 8 MB
    float* val = (float*)(ws + (12u << 20) + 98304);   // 8 MB  (~20.1 MB total)

    k1_map<<<N_NODES / 4, 256, 0, stream>>>(feat, W_map, U, V, h, s, t);
    k23_compact_gat<<<N_NODES / 4, 256, 0, stream>>>(
        sup, h, s, t, b_map, cnt, col, val, gat);
    k4_gcn<<<N_NODES / 4, 256, 0, stream>>>(gat, W_gcn, cnt, col, val, out);
}

// Round 7
// 400.513 us; speedup vs baseline: 1.1212x; 1.0121x over previous
//
#include <hip/hip_runtime.h>

// AttGNN: GAT + GCN on sparse (~1%) 8192-node graph.
// R8: R7 topology + PADDED gather lists. Compacted lists are padded to a
// multiple of 32 with (col=0, w=0) entries -> gather loops are UNCONDITIONAL
// (no per-lane exec-masked loads) and unrolled to 8 outstanding float4
// loads/lane. Attacks the measured 3x-over-BW-floor latency of the K23
// Phase-C and K4 gathers (174 MB L2 traffic, 5 us floor, ~16-18 us observed).
// Cooperative grid.sync quarantined (R2/R3 container kills).
// Floor = sup stream (~35-41 us) + ~320 us harness poison-fill in dur_us.

#define N_NODES 8192
#define D_IN    128
#define D_GAT   64
#define SLOTS   256          // max nnz/row; binomial(8192,0.01) mean ~83, max ~120

// Compact 4 consecutive elements (one float4) of row j held by this lane
// into LDS (clr/vvr). Wave-private: `base` is wave-uniform, no atomics.
#define COMPACT4(VX, QQ)                                                      \
    {                                                                         \
        float ee4[4] = {VX.x, VX.y, VX.z, VX.w};                              \
        _Pragma("unroll")                                                     \
        for (int u = 0; u < 4; ++u) {                                         \
            const int i = (QQ) * 4 + u;                                       \
            const float vv = ee4[u] + ((i == j) ? 1.0f : 0.0f); /* sup2 */    \
            const bool keep = vv > 0.f;                                       \
            const unsigned long long mask = __ballot(keep);                   \
            if (keep) {                                                       \
                const int pos = base +                                        \
                    __popcll(mask & ((1ull << lane) - 1ull));                 \
                if (pos < SLOTS) { clr[pos] = i; vvr[pos] = vv; }             \
            }                                                                 \
            base += __popcll(mask);                                           \
        }                                                                     \
    }

// One unconditional gather batch: 8 outstanding float4 loads (slots p0..p7),
// 4 accumulators. SRC = table to gather from, WARR = weight array in LDS.
#define GATHER32(SRC, WARR, CARR)                                             \
    {                                                                         \
        const int p0 = bse + pp,  p1 = p0 + 4,  p2 = p0 + 8,  p3 = p0 + 12;   \
        const int p4 = p0 + 16,   p5 = p0 + 20, p6 = p0 + 24, p7 = p0 + 28;   \
        const float e0 = WARR[p0], e1 = WARR[p1], e2 = WARR[p2], e3 = WARR[p3];\
        const float e4 = WARR[p4], e5 = WARR[p5], e6 = WARR[p6], e7 = WARR[p7];\
        const float4 v0 = *(const float4*)(SRC + CARR[p0] * D_GAT + c16);     \
        const float4 v1 = *(const float4*)(SRC + CARR[p1] * D_GAT + c16);     \
        const float4 v2 = *(const float4*)(SRC + CARR[p2] * D_GAT + c16);     \
        const float4 v3 = *(const float4*)(SRC + CARR[p3] * D_GAT + c16);     \
        const float4 v4 = *(const float4*)(SRC + CARR[p4] * D_GAT + c16);     \
        const float4 v5 = *(const float4*)(SRC + CARR[p5] * D_GAT + c16);     \
        const float4 v6 = *(const float4*)(SRC + CARR[p6] * D_GAT + c16);     \
        const float4 v7 = *(const float4*)(SRC + CARR[p7] * D_GAT + c16);     \
        a0.x += e0*v0.x; a0.y += e0*v0.y; a0.z += e0*v0.z; a0.w += e0*v0.w;   \
        a1.x += e1*v1.x; a1.y += e1*v1.y; a1.z += e1*v1.z; a1.w += e1*v1.w;   \
        a2.x += e2*v2.x; a2.y += e2*v2.y; a2.z += e2*v2.z; a2.w += e2*v2.w;   \
        a3.x += e3*v3.x; a3.y += e3*v3.y; a3.z += e3*v3.z; a3.w += e3*v3.w;   \
        a0.x += e4*v4.x; a0.y += e4*v4.y; a0.z += e4*v4.z; a0.w += e4*v4.w;   \
        a1.x += e5*v5.x; a1.y += e5*v5.y; a1.z += e5*v5.z; a1.w += e5*v5.w;   \
        a2.x += e6*v6.x; a2.y += e6*v6.y; a2.z += e6*v6.z; a2.w += e6*v6.w;   \
        a3.x += e7*v7.x; a3.y += e7*v7.y; a3.z += e7*v7.z; a3.w += e7*v7.w;   \
    }

// ---------------- K1: h = feat@W_map ; s = h@U ; t = h@V --------------------
__global__ __launch_bounds__(256) void k1_map(
    const float* __restrict__ feat, const float* __restrict__ W_map,
    const float* __restrict__ U, const float* __restrict__ V,
    float* __restrict__ h, float* __restrict__ s, float* __restrict__ t)
{
    const int wid  = threadIdx.x >> 6;
    const int lane = threadIdx.x & 63;
    const int row = blockIdx.x * 4 + wid;
    __shared__ float f[4 * D_IN];
    if (threadIdx.x < 128)
        ((float4*)f)[threadIdx.x] =
            ((const float4*)(feat + (size_t)blockIdx.x * 4 * D_IN))[threadIdx.x];
    __syncthreads();
    const float* fr = f + wid * D_IN;
    float acc = 0.f;
#pragma unroll 8
    for (int k = 0; k < D_IN; ++k)
        acc += fr[k] * W_map[k * D_GAT + lane];
    h[row * D_GAT + lane] = acc;
    float sv = acc * U[lane];
    float tv = acc * V[lane];
#pragma unroll
    for (int off = 32; off > 0; off >>= 1) {
        sv += __shfl_xor(sv, off);
        tv += __shfl_xor(tv, off);
    }
    if (lane == 0) { s[row] = sv; t[row] = tv; }
}

// ---------------- K23: compact sup2 row j -> LDS, then GAT row j ------------
// Phase A: stream row (4-deep), ballot-compact into LDS.
// Phase B: one pass: pad list to mult-of-32 (col=0,w=0), write-through
//          (col,val,padded cnt) for K4, w=exp(tanh(s_i+tj)) [no-max: tanh
//          in [-1,1], exp can't overflow], lsum.
// Phase C: UNCONDITIONAL (pp,c16) gather, 8 outstanding float4/lane.
__global__ __launch_bounds__(256) void k23_compact_gat(
    const float* __restrict__ sup, const float* __restrict__ h,
    const float* __restrict__ s, const float* __restrict__ t,
    const float* __restrict__ b,
    int* __restrict__ cnt, int* __restrict__ col, float* __restrict__ val,
    float* __restrict__ gat)
{
    const int wid  = threadIdx.x >> 6;
    const int lane = threadIdx.x & 63;
    const int j = blockIdx.x * 4 + wid;

    __shared__ int   cl_s[4][SLOTS];   // 4 KB  compacted neighbor cols
    __shared__ float vv_s[4][SLOTS];   // 4 KB  compacted sup2 values
    __shared__ float w_s[4][SLOTS];    // 4 KB  softmax weights
    int*   clr = cl_s[wid];
    float* vvr = vv_s[wid];
    float* w   = w_s[wid];

    // --- Phase A: stream 32 KB row, 4 outstanding float4/lane ---
    const float4* row4 = (const float4*)(sup + (size_t)j * N_NODES);
    int base = 0;                          // wave-uniform running count
    for (int q = lane; q < N_NODES / 4; q += 256) {
        float4 v0 = row4[q];
        float4 v1 = row4[q + 64];
        float4 v2 = row4[q + 128];
        float4 v3 = row4[q + 192];
        COMPACT4(v0, q);
        COMPACT4(v1, q + 64);
        COMPACT4(v2, q + 128);
        COMPACT4(v3, q + 192);
    }
    const int m     = (base < SLOTS) ? base : SLOTS;
    const int m_pad = (m + 31) & ~31;      // SLOTS=256 is a mult of 32: safe
    __syncthreads();                       // LDS lists visible across lanes

    // --- Phase B: pad + K4 write-through + w=exp(tanh(s_i+tj)) + lsum ---
    int*   colj = col + j * SLOTS;
    float* valj = val + j * SLOTS;
    const float tj = t[j] + b[0];
    float lsum = 0.f;
    for (int p = lane; p < m_pad; p += 64) {
        if (p < m) {
            const int ci = clr[p];
            colj[p] = ci;
            valj[p] = vvr[p];
            const float e = __expf(tanhf(s[ci] + tj));
            w[p] = e;
            lsum += e;
        } else {                            // pad entry: no-op in all sums
            clr[p] = 0; w[p] = 0.f;
            colj[p] = 0; valj[p] = 0.f;
        }
    }
    if (lane == 0) cnt[j] = m_pad;
#pragma unroll
    for (int off = 32; off > 0; off >>= 1) lsum += __shfl_xor(lsum, off);
    __syncthreads();                       // w[], pads visible across lanes

    // --- Phase C: unconditional gather over h, 8 outstanding/iter ---
    const int c16 = (lane & 15) * 4;
    const int pp  = lane >> 4;
    float4 a0 = make_float4(0,0,0,0), a1 = a0, a2 = a0, a3 = a0;
    for (int bse = 0; bse < m_pad; bse += 32)
        GATHER32(h, w, clr);
    float4 acc;
    acc.x = (a0.x + a1.x) + (a2.x + a3.x);
    acc.y = (a0.y + a1.y) + (a2.y + a3.y);
    acc.z = (a0.z + a1.z) + (a2.z + a3.z);
    acc.w = (a0.w + a1.w) + (a2.w + a3.w);
#pragma unroll
    for (int off = 16; off <= 32; off <<= 1) {
        acc.x += __shfl_xor(acc.x, off); acc.y += __shfl_xor(acc.y, off);
        acc.z += __shfl_xor(acc.z, off); acc.w += __shfl_xor(acc.w, off);
    }
    if (pp == 0) {
        const float inv = 1.0f / lsum;
        float4 o;
        o.x = tanhf(acc.x * inv); o.y = tanhf(acc.y * inv);
        o.z = tanhf(acc.z * inv); o.w = tanhf(acc.w * inv);
        *(float4*)(gat + j * D_GAT + c16) = o;
    }
}

// ---------------- K4: agg = sup2@gat ; out = normalize(relu(agg@W_gcn)) ----
// cnt[j] is pre-padded (mult of 32, val pads = 0) -> unconditional gather.
__global__ __launch_bounds__(256) void k4_gcn(
    const float* __restrict__ gat, const float* __restrict__ W_gcn,
    const int* __restrict__ cnt, const int* __restrict__ col,
    const float* __restrict__ val, float* __restrict__ out)
{
    const int wid  = threadIdx.x >> 6;
    const int lane = threadIdx.x & 63;
    const int j = blockIdx.x * 4 + wid;
    const int m = cnt[j];                  // padded count
    const int*   colj = col + j * SLOTS;
    const float* valj = val + j * SLOTS;
    __shared__ int   cl_s[4][SLOTS];
    __shared__ float wv_s[4][SLOTS];
    __shared__ float a_s[4][D_GAT];
    int*   cl = cl_s[wid];
    float* wv = wv_s[wid];
    float* a  = a_s[wid];
    for (int p = lane; p < m; p += 64) { cl[p] = colj[p]; wv[p] = valj[p]; }
    __syncthreads();

    const int c16 = (lane & 15) * 4;
    const int pp  = lane >> 4;
    float4 a0 = make_float4(0,0,0,0), a1 = a0, a2 = a0, a3 = a0;
    for (int bse = 0; bse < m; bse += 32)
        GATHER32(gat, wv, cl);
    float4 acc;
    acc.x = (a0.x + a1.x) + (a2.x + a3.x);
    acc.y = (a0.y + a1.y) + (a2.y + a3.y);
    acc.z = (a0.z + a1.z) + (a2.z + a3.z);
    acc.w = (a0.w + a1.w) + (a2.w + a3.w);
#pragma unroll
    for (int off = 16; off <= 32; off <<= 1) {
        acc.x += __shfl_xor(acc.x, off); acc.y += __shfl_xor(acc.y, off);
        acc.z += __shfl_xor(acc.z, off); acc.w += __shfl_xor(acc.w, off);
    }
    if (pp == 0) *(float4*)(a + c16) = acc;
    __syncthreads();     // a_s visibility (intra-wave, but keep it simple/safe)

    float o = 0.f;
#pragma unroll 8
    for (int d = 0; d < D_GAT; ++d)
        o += a[d] * W_gcn[d * D_GAT + lane];   // a broadcast, W_gcn L1-hot
    o = fmaxf(o, 0.f);

    float ss = o * o;
#pragma unroll
    for (int off = 32; off > 0; off >>= 1) ss += __shfl_xor(ss, off);
    const float nrm = sqrtf(ss);
    out[j * D_GAT + lane] = o / fmaxf(nrm, 1e-12f);
}

extern "C" void kernel_launch(void* const* d_in, const int* in_sizes, int n_in,
                              void* d_out, int out_size, void* d_ws, size_t ws_size,
                              hipStream_t stream) {
    const float* feat  = (const float*)d_in[0];  // [N,128]
    const float* sup   = (const float*)d_in[1];  // [N,N]
    const float* W_map = (const float*)d_in[2];  // [128,64]
    const float* b_map = (const float*)d_in[3];  // [1]
    const float* U     = (const float*)d_in[4];  // [64,1]
    const float* V     = (const float*)d_in[5];  // [64,1]
    const float* W_gcn = (const float*)d_in[6];  // [64,64]
    float* out = (float*)d_out;

    char* ws = (char*)d_ws;
    float* h   = (float*)(ws);                         // 2 MB
    float* gat = (float*)(ws + (2u << 20));            // 2 MB
    float* s   = (float*)(ws + (4u << 20));            // 32 KB
    float* t   = (float*)(ws + (4u << 20) + 32768);    // 32 KB
    int*   cnt = (int*)  (ws + (4u << 20) + 65536);    // 32 KB
    int*   col = (int*)  (ws + (4u << 20) + 98304);    // 8 MB
    float* val = (float*)(ws + (12u << 20) + 98304);   // 8 MB  (~20.1 MB total)

    k1_map<<<N_NODES / 4, 256, 0, stream>>>(feat, W_map, U, V, h, s, t);
    k23_compact_gat<<<N_NODES / 4, 256, 0, stream>>>(
        sup, h, s, t, b_map, cnt, col, val, gat);
    k4_gcn<<<N_NODES / 4, 256, 0, stream>>>(gat, W_gcn, cnt, col, val, out);
}

// Round 8
// 400.188 us; speedup vs baseline: 1.1221x; 1.0008x over previous
//
#include <hip/hip_runtime.h>

// AttGNN: GAT + GCN on sparse (~1%) 8192-node graph.
// R9: R8 + algebraic K4 slim: (sup2@gat)@W_gcn == sup2@(gat@W_gcn), so K23's
// epilogue computes g2 = gat_row@W_gcn (row is live in LDS; W_gcn L1-hot) and
// K4 becomes pure gather+relu+normalize: no a_s staging, no 2nd barrier, no
// matmul, norm via shuffles only. (col,val) packed as float2 (one 8B op per
// entry each side). Gather lists stay padded to mult-of-32 (R8 win: -5 us).
// Cooperative grid.sync quarantined (R2/R3 container kills).
// Floor = sup stream (~35-41 us; ~40% L3-hit per R6) + ~320 us harness
// poison-fill visible in dur_us.

#define N_NODES 8192
#define D_IN    128
#define D_GAT   64
#define SLOTS   256          // max nnz/row; binomial(8192,0.01) mean ~83, max ~120

// Compact 4 consecutive elements (one float4) of row j held by this lane
// into LDS (clr/vvr). Wave-private: `base` is wave-uniform, no atomics.
#define COMPACT4(VX, QQ)                                                      \
    {                                                                         \
        float ee4[4] = {VX.x, VX.y, VX.z, VX.w};                              \
        _Pragma("unroll")                                                     \
        for (int u = 0; u < 4; ++u) {                                         \
            const int i = (QQ) * 4 + u;                                       \
            const float vv = ee4[u] + ((i == j) ? 1.0f : 0.0f); /* sup2 */    \
            const bool keep = vv > 0.f;                                       \
            const unsigned long long mask = __ballot(keep);                   \
            if (keep) {                                                       \
                const int pos = base +                                        \
                    __popcll(mask & ((1ull << lane) - 1ull));                 \
                if (pos < SLOTS) { clr[pos] = i; vvr[pos] = vv; }             \
            }                                                                 \
            base += __popcll(mask);                                           \
        }                                                                     \
    }

// One unconditional gather batch: 8 outstanding float4 loads (slots p0..p7),
// 4 accumulators. SRC = table to gather from, WARR/CARR = weights/cols (LDS).
#define GATHER32(SRC, WARR, CARR)                                             \
    {                                                                         \
        const int p0 = bse + pp,  p1 = p0 + 4,  p2 = p0 + 8,  p3 = p0 + 12;   \
        const int p4 = p0 + 16,   p5 = p0 + 20, p6 = p0 + 24, p7 = p0 + 28;   \
        const float e0 = WARR[p0], e1 = WARR[p1], e2 = WARR[p2], e3 = WARR[p3];\
        const float e4 = WARR[p4], e5 = WARR[p5], e6 = WARR[p6], e7 = WARR[p7];\
        const float4 v0 = *(const float4*)(SRC + CARR[p0] * D_GAT + c16);     \
        const float4 v1 = *(const float4*)(SRC + CARR[p1] * D_GAT + c16);     \
        const float4 v2 = *(const float4*)(SRC + CARR[p2] * D_GAT + c16);     \
        const float4 v3 = *(const float4*)(SRC + CARR[p3] * D_GAT + c16);     \
        const float4 v4 = *(const float4*)(SRC + CARR[p4] * D_GAT + c16);     \
        const float4 v5 = *(const float4*)(SRC + CARR[p5] * D_GAT + c16);     \
        const float4 v6 = *(const float4*)(SRC + CARR[p6] * D_GAT + c16);     \
        const float4 v7 = *(const float4*)(SRC + CARR[p7] * D_GAT + c16);     \
        a0.x += e0*v0.x; a0.y += e0*v0.y; a0.z += e0*v0.z; a0.w += e0*v0.w;   \
        a1.x += e1*v1.x; a1.y += e1*v1.y; a1.z += e1*v1.z; a1.w += e1*v1.w;   \
        a2.x += e2*v2.x; a2.y += e2*v2.y; a2.z += e2*v2.z; a2.w += e2*v2.w;   \
        a3.x += e3*v3.x; a3.y += e3*v3.y; a3.z += e3*v3.z; a3.w += e3*v3.w;   \
        a0.x += e4*v4.x; a0.y += e4*v4.y; a0.z += e4*v4.z; a0.w += e4*v4.w;   \
        a1.x += e5*v5.x; a1.y += e5*v5.y; a1.z += e5*v5.z; a1.w += e5*v5.w;   \
        a2.x += e6*v6.x; a2.y += e6*v6.y; a2.z += e6*v6.z; a2.w += e6*v6.w;   \
        a3.x += e7*v7.x; a3.y += e7*v7.y; a3.z += e7*v7.z; a3.w += e7*v7.w;   \
    }

// ---------------- K1: h = feat@W_map ; s = h@U ; t = h@V --------------------
__global__ __launch_bounds__(256) void k1_map(
    const float* __restrict__ feat, const float* __restrict__ W_map,
    const float* __restrict__ U, const float* __restrict__ V,
    float* __restrict__ h, float* __restrict__ s, float* __restrict__ t)
{
    const int wid  = threadIdx.x >> 6;
    const int lane = threadIdx.x & 63;
    const int row = blockIdx.x * 4 + wid;
    __shared__ float f[4 * D_IN];
    if (threadIdx.x < 128)
        ((float4*)f)[threadIdx.x] =
            ((const float4*)(feat + (size_t)blockIdx.x * 4 * D_IN))[threadIdx.x];
    __syncthreads();
    const float* fr = f + wid * D_IN;
    float acc = 0.f;
#pragma unroll 8
    for (int k = 0; k < D_IN; ++k)
        acc += fr[k] * W_map[k * D_GAT + lane];
    h[row * D_GAT + lane] = acc;
    float sv = acc * U[lane];
    float tv = acc * V[lane];
#pragma unroll
    for (int off = 32; off > 0; off >>= 1) {
        sv += __shfl_xor(sv, off);
        tv += __shfl_xor(tv, off);
    }
    if (lane == 0) { s[row] = sv; t[row] = tv; }
}

// ---------------- K23: compact sup2 row j -> GAT -> g2 = gat@W_gcn ----------
// Phase A: stream row (4-deep), ballot-compact into LDS.
// Phase B: pad to mult-of-32, write-through packed (col,val) float2 for K4,
//          w = exp(tanh(s_i+tj)) [no-max: tanh in [-1,1]], lsum.
// Phase C: unconditional (pp,c16) gather over h, 8 outstanding float4/lane.
// Epilogue: gat row -> LDS, g2[j] = gat_row @ W_gcn (W_gcn L1-hot).
__global__ __launch_bounds__(256) void k23_compact_gat(
    const float* __restrict__ sup, const float* __restrict__ h,
    const float* __restrict__ s, const float* __restrict__ t,
    const float* __restrict__ b, const float* __restrict__ W_gcn,
    int* __restrict__ cnt, float2* __restrict__ colval,
    float* __restrict__ g2)
{
    const int wid  = threadIdx.x >> 6;
    const int lane = threadIdx.x & 63;
    const int j = blockIdx.x * 4 + wid;

    __shared__ int   cl_s[4][SLOTS];   // 4 KB  compacted neighbor cols
    __shared__ float vv_s[4][SLOTS];   // 4 KB  compacted sup2 values
    __shared__ float w_s[4][SLOTS];    // 4 KB  softmax weights
    int*   clr = cl_s[wid];
    float* vvr = vv_s[wid];
    float* w   = w_s[wid];

    // --- Phase A: stream 32 KB row, 4 outstanding float4/lane ---
    const float4* row4 = (const float4*)(sup + (size_t)j * N_NODES);
    int base = 0;                          // wave-uniform running count
    for (int q = lane; q < N_NODES / 4; q += 256) {
        float4 v0 = row4[q];
        float4 v1 = row4[q + 64];
        float4 v2 = row4[q + 128];
        float4 v3 = row4[q + 192];
        COMPACT4(v0, q);
        COMPACT4(v1, q + 64);
        COMPACT4(v2, q + 128);
        COMPACT4(v3, q + 192);
    }
    const int m     = (base < SLOTS) ? base : SLOTS;
    const int m_pad = (m + 31) & ~31;      // SLOTS=256 is a mult of 32: safe
    __syncthreads();                       // LDS lists visible across lanes

    // --- Phase B: pad + packed K4 write-through + w=exp(tanh) + lsum ---
    float2* cvj = colval + j * SLOTS;
    const float tj = t[j] + b[0];
    float lsum = 0.f;
    for (int p = lane; p < m_pad; p += 64) {
        if (p < m) {
            const int ci = clr[p];
            cvj[p] = make_float2(__int_as_float(ci), vvr[p]);
            const float e = __expf(tanhf(s[ci] + tj));
            w[p] = e;
            lsum += e;
        } else {                            // pad entry: no-op in all sums
            clr[p] = 0; w[p] = 0.f;
            cvj[p] = make_float2(__int_as_float(0), 0.f);
        }
    }
    if (lane == 0) cnt[j] = m_pad;
#pragma unroll
    for (int off = 32; off > 0; off >>= 1) lsum += __shfl_xor(lsum, off);
    __syncthreads();                       // w[], pads visible across lanes

    // --- Phase C: unconditional gather over h, 8 outstanding/iter ---
    const int c16 = (lane & 15) * 4;
    const int pp  = lane >> 4;
    float4 a0 = make_float4(0,0,0,0), a1 = a0, a2 = a0, a3 = a0;
    for (int bse = 0; bse < m_pad; bse += 32)
        GATHER32(h, w, clr);
    float4 acc;
    acc.x = (a0.x + a1.x) + (a2.x + a3.x);
    acc.y = (a0.y + a1.y) + (a2.y + a3.y);
    acc.z = (a0.z + a1.z) + (a2.z + a3.z);
    acc.w = (a0.w + a1.w) + (a2.w + a3.w);
#pragma unroll
    for (int off = 16; off <= 32; off <<= 1) {
        acc.x += __shfl_xor(acc.x, off); acc.y += __shfl_xor(acc.y, off);
        acc.z += __shfl_xor(acc.z, off); acc.w += __shfl_xor(acc.w, off);
    }
    // every lane now holds the total for chunk c16=(lane&15)*4
    const float inv = 1.0f / lsum;
    float4 gr;
    gr.x = tanhf(acc.x * inv); gr.y = tanhf(acc.y * inv);
    gr.z = tanhf(acc.z * inv); gr.w = tanhf(acc.w * inv);

    // --- Epilogue: g2[j] = gat_row @ W_gcn (gat row staged in vvr) ---
    if (pp == 0) *(float4*)(vvr + c16) = gr;   // reuse vv_s as gat-row buffer
    __syncthreads();                           // uniform across block
    float o = 0.f;
#pragma unroll 8
    for (int k = 0; k < D_GAT; ++k)
        o += vvr[k] * W_gcn[k * D_GAT + lane]; // vvr broadcast, W_gcn L1-hot
    g2[j * D_GAT + lane] = o;
}

// ---------------- K4: out = normalize(relu(sup2 @ g2)) ---------------------
// Pure gather+relu+normalize: lists pre-padded (mult of 32, val pads = 0),
// no a_s staging, no matmul, norm entirely in shuffles.
__global__ __launch_bounds__(256) void k4_gcn(
    const float* __restrict__ g2, const int* __restrict__ cnt,
    const float2* __restrict__ colval, float* __restrict__ out)
{
    const int wid  = threadIdx.x >> 6;
    const int lane = threadIdx.x & 63;
    const int j = blockIdx.x * 4 + wid;
    const int m = cnt[j];                  // padded count
    const float2* cvj = colval + j * SLOTS;
    __shared__ int   cl_s[4][SLOTS];
    __shared__ float wv_s[4][SLOTS];
    int*   cl = cl_s[wid];
    float* wv = wv_s[wid];
    for (int p = lane; p < m; p += 64) {
        const float2 cv = cvj[p];
        cl[p] = __float_as_int(cv.x);
        wv[p] = cv.y;
    }
    __syncthreads();

    const int c16 = (lane & 15) * 4;
    const int pp  = lane >> 4;
    float4 a0 = make_float4(0,0,0,0), a1 = a0, a2 = a0, a3 = a0;
    for (int bse = 0; bse < m; bse += 32)
        GATHER32(g2, wv, cl);
    float4 acc;
    acc.x = (a0.x + a1.x) + (a2.x + a3.x);
    acc.y = (a0.y + a1.y) + (a2.y + a3.y);
    acc.z = (a0.z + a1.z) + (a2.z + a3.z);
    acc.w = (a0.w + a1.w) + (a2.w + a3.w);
#pragma unroll
    for (int off = 16; off <= 32; off <<= 1) {
        acc.x += __shfl_xor(acc.x, off); acc.y += __shfl_xor(acc.y, off);
        acc.z += __shfl_xor(acc.z, off); acc.w += __shfl_xor(acc.w, off);
    }
    // every lane holds the agg total for chunk (lane&15); relu then norm
    float4 o4;
    o4.x = fmaxf(acc.x, 0.f); o4.y = fmaxf(acc.y, 0.f);
    o4.z = fmaxf(acc.z, 0.f); o4.w = fmaxf(acc.w, 0.f);
    float ss = (o4.x*o4.x + o4.y*o4.y) + (o4.z*o4.z + o4.w*o4.w);
#pragma unroll
    for (int off = 1; off <= 8; off <<= 1) ss += __shfl_xor(ss, off);
    const float inv = 1.0f / fmaxf(sqrtf(ss), 1e-12f);
    if (pp == 0) {
        float4 o;
        o.x = o4.x * inv; o.y = o4.y * inv;
        o.z = o4.z * inv; o.w = o4.w * inv;
        *(float4*)(out + j * D_GAT + c16) = o;
    }
}

extern "C" void kernel_launch(void* const* d_in, const int* in_sizes, int n_in,
                              void* d_out, int out_size, void* d_ws, size_t ws_size,
                              hipStream_t stream) {
    const float* feat  = (const float*)d_in[0];  // [N,128]
    const float* sup   = (const float*)d_in[1];  // [N,N]
    const float* W_map = (const float*)d_in[2];  // [128,64]
    const float* b_map = (const float*)d_in[3];  // [1]
    const float* U     = (const float*)d_in[4];  // [64,1]
    const float* V     = (const float*)d_in[5];  // [64,1]
    const float* W_gcn = (const float*)d_in[6];  // [64,64]
    float* out = (float*)d_out;

    char* ws = (char*)d_ws;
    float*  h      = (float*)(ws);                        // 2 MB
    float*  g2     = (float*)(ws + (2u << 20));           // 2 MB
    float*  s      = (float*)(ws + (4u << 20));           // 32 KB
    float*  t      = (float*)(ws + (4u << 20) + 32768);   // 32 KB
    int*    cnt    = (int*)  (ws + (4u << 20) + 65536);   // 32 KB
    float2* colval = (float2*)(ws + (4u << 20) + 98304);  // 16 MB (~20.1 MB)

    k1_map<<<N_NODES / 4, 256, 0, stream>>>(feat, W_map, U, V, h, s, t);
    k23_compact_gat<<<N_NODES / 4, 256, 0, stream>>>(
        sup, h, s, t, b_map, W_gcn, cnt, colval, g2);
    k4_gcn<<<N_NODES / 4, 256, 0, stream>>>(g2, cnt, colval, out);
}